// Round 10
// baseline (201.907 us; speedup 1.0000x reference)
//
#include <hip/hip_runtime.h>
#include <hip/hip_bf16.h>

#define DIMSZ 256
#define HID 4096
#define BATCH 4
#define SEQ 2048
#define NCH 64      // chunks per sequence (carry granularity)
#define CLEN 32     // chunk length
#define SPLITK2 4   // K-splits for fused GEMM2
#define KCHUNK (HID / SPLITK2)   // 1024 channels per block
#define BM2 64      // timesteps per fused-GEMM2 block

typedef __bf16 bf16_t;
typedef __bf16 bf16x8 __attribute__((ext_vector_type(8)));
typedef float  f32x4  __attribute__((ext_vector_type(4)));

__device__ __forceinline__ float sigmoidf_dev(float x) {
    return 1.0f / (1.0f + __expf(-x));
}

// async global->LDS, 16B/lane. LDS dest = wave-uniform base + lane*16.
__device__ __forceinline__ void load_lds16(const bf16_t* g, bf16_t* l) {
    __builtin_amdgcn_global_load_lds(
        (const __attribute__((address_space(1))) void*)g,
        (__attribute__((address_space(3))) void*)l,
        16, 0, 0);
}

__device__ __forceinline__ bf16x8 cvt8(const float* p) {
    bf16x8 o;
    #pragma unroll
    for (int j = 0; j < 8; j++) o[j] = (bf16_t)p[j];
    return o;
}

// ---------------- prep: fused fp32->bf16 convert + MFMA-frag swizzle ----------------
// xt : [ks][m16][lane][8]  ks=k>>5 (0..7),  m16=m>>4 (0..511)
// WBt: [ks][n16][lane][8]  ks 0..7, n16 0..255
// Wt : [ks][g][lane][8]    ks 0..127, g 0..15
__global__ void prep_kernel(const float* __restrict__ x,
                            const float* __restrict__ WB,
                            const float* __restrict__ WC,
                            bf16_t* __restrict__ xt,
                            bf16_t* __restrict__ WBt,
                            bf16_t* __restrict__ Wt) {
    int i = blockIdx.x * blockDim.x + threadIdx.x;   // 524288
    if (i < 262144) {                                // xt
        int lane = i & 63, m16 = (i >> 6) & 511, ks = i >> 15;
        int row = m16 * 16 + (lane & 15);
        int k   = ks * 32 + (lane >> 4) * 8;
        *(bf16x8*)&xt[(size_t)i * 8] = cvt8(&x[(size_t)row * DIMSZ + k]);
    } else if (i < 393216) {                         // WBt
        int j = i - 262144;
        int lane = j & 63, n16 = (j >> 6) & 255, ks = j >> 14;
        int row = n16 * 16 + (lane & 15);
        int k   = ks * 32 + (lane >> 4) * 8;
        *(bf16x8*)&WBt[(size_t)j * 8] = cvt8(&WB[(size_t)row * DIMSZ + k]);
    } else {                                         // Wt
        int j = i - 393216;
        int lane = j & 63, g = (j >> 6) & 15, ks = j >> 10;
        int row = g * 16 + (lane & 15);
        int k   = ks * 32 + (lane >> 4) * 8;
        *(bf16x8*)&Wt[(size_t)j * 8] = cvt8(&WC[(size_t)row * HID + k]);
    }
}

// ---------------- GEMM1 fused: b = x@WB^T + bB (bf16), + per-chunk totals ----------------
// Barrier-free K-loop: frags stream from pre-swizzled xt/WBt (L2-hot) to VGPRs.
__global__ __launch_bounds__(256)
void gemm1_fused(const bf16_t* __restrict__ xt, const bf16_t* __restrict__ WBt,
                 const float* __restrict__ bias, const float* __restrict__ Adecay,
                 bf16_t* __restrict__ Cg, float* __restrict__ totals)
{
    constexpr int N = HID;
    constexpr int LDTILE = 136;
    __shared__ bf16_t tile[128 * LDTILE];   // 34 KB

    const int tid = threadIdx.x, wave = tid >> 6, lane = tid & 63;
    const int wm = wave >> 1, wn = wave & 1, q = lane >> 4, r16 = lane & 15;
    const int mBase = blockIdx.x * 128, nBase = blockIdx.y * 128;
    const int m16Base = blockIdx.x * 8 + wm * 4;
    const int n16Base = blockIdx.y * 8 + wn * 4;

    f32x4 acc[4][4] = {};

    #pragma unroll 2
    for (int ks = 0; ks < 8; ks++) {
        bf16x8 af[4], bfr[4];
        #pragma unroll
        for (int mt = 0; mt < 4; mt++)
            af[mt] = *(const bf16x8*)&xt[(((size_t)ks * 512 + m16Base + mt) * 64 + lane) * 8];
        #pragma unroll
        for (int nt = 0; nt < 4; nt++)
            bfr[nt] = *(const bf16x8*)&WBt[(((size_t)ks * 256 + n16Base + nt) * 64 + lane) * 8];
        #pragma unroll
        for (int mt = 0; mt < 4; mt++)
            #pragma unroll
            for (int nt = 0; nt < 4; nt++)
                acc[mt][nt] = __builtin_amdgcn_mfma_f32_16x16x32_bf16(
                    af[mt], bfr[nt], acc[mt][nt], 0, 0, 0);
    }

    // acc (+bias) -> LDS tile
    #pragma unroll
    for (int nt = 0; nt < 4; nt++) {
        const int chl = wn * 64 + nt * 16 + r16;
        const float bv = bias[nBase + chl];
        #pragma unroll
        for (int mt = 0; mt < 4; mt++) {
            const int t0 = wm * 64 + mt * 16 + q * 4;
            #pragma unroll
            for (int rg = 0; rg < 4; rg++)
                tile[(t0 + rg) * LDTILE + chl] = (bf16_t)(acc[mt][nt][rg] + bv);
        }
    }
    __syncthreads();

    // coalesced writeback: 8 passes x (16 rows x 128 ch)
    #pragma unroll
    for (int p = 0; p < 8; p++) {
        const int t = p * 16 + (tid >> 4);
        const int ch8 = (tid & 15) << 3;
        *(bf16x8*)&Cg[(size_t)(mBase + t) * N + nBase + ch8] =
            *(const bf16x8*)&tile[t * LDTILE + ch8];
    }

    // chunk totals: 128 channels x 4 chunks
    #pragma unroll
    for (int t = 0; t < 2; t++) {
        int task = tid + t * 256;
        int ch = task & 127, ck = task >> 7;
        float a = sigmoidf_dev(Adecay[nBase + ch]);
        float tot = 0.f;
        #pragma unroll 8
        for (int i = 0; i < CLEN; i++)
            tot = a * tot + (float)tile[(ck * CLEN + i) * LDTILE + ch];
        int batch = mBase >> 11;
        int cg = ((mBase & 2047) >> 5) + ck;
        totals[(size_t)(batch * NCH + cg) * HID + nBase + ch] = tot;
    }
}

// ---------------- fused scan + GEMM2 split-K, barrier-free MFMA K-loop ----------------
// Carry prefix computed in-kernel from totals (scan_carries kernel removed);
// scan split into 2x32-step chains (chunk-aligned) for 2x ILP.
__global__ __launch_bounds__(256)
void gemm2_fused(const bf16_t* __restrict__ bv, const bf16_t* __restrict__ Wt,
                 const float* __restrict__ Adecay, const float* __restrict__ totals,
                 float* __restrict__ P)
{
    constexpr int N = DIMSZ;
    constexpr int CKSTRIDE = BM2 * 32 + 32;    // +64B stagger between ck slabs
    __shared__ bf16_t hs[8 * CKSTRIDE];        // 32.5 KB

    const int tid = threadIdx.x, wave = tid >> 6, lane = tid & 63;
    const int q = lane >> 4, r16 = lane & 15;
    const int mBase = blockIdx.x * BM2;
    const int kBase = blockIdx.y * KCHUNK;
    const int batch = mBase >> 11;
    const int chunk0 = (mBase & 2047) >> 5;    // wave-uniform

    f32x4 acc[4][4] = {};

    for (int s = 0; s < KCHUNK / 256; s++) {
        const int chSlab = kBase + s * 256;

        // all waves must finish the previous slab's hs reads before DMA writes land
        if (s > 0) __syncthreads();

        // stage b-slab -> hs: wave w covers cks {2w, 2w+1}, 4 row-groups each
        #pragma unroll
        for (int i = 0; i < 8; i++) {
            int ck = wave * 2 + (i >> 2);
            int g  = i & 3;
            load_lds16(&bv[(size_t)(mBase + g * 16 + (lane >> 2)) * HID
                           + chSlab + ck * 32 + ((lane & 3) << 3)],
                       &hs[ck * CKSTRIDE + g * 512]);
        }

        // carry prefix from totals (overlaps with staging; wave-uniform trip count)
        const int ck = tid >> 5, ch = tid & 31;
        const int c = chSlab + ck * 32 + ch;
        const float a = sigmoidf_dev(Adecay[c]);
        float aC = a;
        #pragma unroll
        for (int i = 0; i < 5; i++) aC *= aC;  // a^32
        const float* tp = &totals[(size_t)batch * NCH * HID + c];
        float carry0 = 0.f;
        for (int cc = 0; cc < chunk0; cc++)
            carry0 = aC * carry0 + tp[(size_t)cc * HID];
        const float carry1 = aC * carry0 + tp[(size_t)chunk0 * HID];

        __syncthreads();   // staging drained

        // in-place scan: 2 independent 32-step chains (chunk-aligned seeds)
        {
            bf16_t* hp = &hs[ck * CKSTRIDE + ch];
            float st0 = carry0, st1 = carry1;
            #pragma unroll 8
            for (int t = 0; t < 32; t++) {
                st0 = a * st0 + (float)hp[t * 32];
                st1 = a * st1 + (float)hp[(t + 32) * 32];
                hp[t * 32]        = (bf16_t)st0;
                hp[(t + 32) * 32] = (bf16_t)st1;
            }
        }
        __syncthreads();   // hs = h, visible to all waves

        // barrier-free MFMA k-steps; B-frags direct from swizzled global
        const int ksBase = (kBase >> 5) + s * 8;
        #pragma unroll 2
        for (int cki = 0; cki < 8; cki++) {
            bf16x8 af[4], bfr[4];
            #pragma unroll
            for (int nt = 0; nt < 4; nt++)
                bfr[nt] = *(const bf16x8*)&Wt[
                    (((size_t)(ksBase + cki) * 16 + wave * 4 + nt) * 64 + lane) * 8];
            #pragma unroll
            for (int mt = 0; mt < 4; mt++)
                af[mt] = *(const bf16x8*)&hs[cki * CKSTRIDE + (mt * 16 + r16) * 32 + q * 8];
            #pragma unroll
            for (int mt = 0; mt < 4; mt++)
                #pragma unroll
                for (int nt = 0; nt < 4; nt++)
                    acc[mt][nt] = __builtin_amdgcn_mfma_f32_16x16x32_bf16(
                        af[mt], bfr[nt], acc[mt][nt], 0, 0, 0);
        }
    }

    // epilogue: fp32 partials
    float* Pb = P + (size_t)blockIdx.y * (BATCH * SEQ) * N;
    #pragma unroll
    for (int nt = 0; nt < 4; nt++) {
        const int col = wave * 64 + nt * 16 + r16;
        #pragma unroll
        for (int mt = 0; mt < 4; mt++) {
            const int row0 = mBase + mt * 16 + q * 4;
            #pragma unroll
            for (int rg = 0; rg < 4; rg++)
                Pb[(size_t)(row0 + rg) * N + col] = acc[mt][nt][rg];
        }
    }
}

// ---------------- reduce partials + bias -> d_out ----------------
__global__ void reduce_out_kernel(const float* __restrict__ P,
                                  const float* __restrict__ bias,
                                  float* __restrict__ out, int MN4) {
    int i = blockIdx.x * blockDim.x + threadIdx.x;
    if (i >= MN4) return;
    int n4 = i & (DIMSZ / 4 - 1);
    float4 acc = ((const float4*)bias)[n4];
    #pragma unroll
    for (int s = 0; s < SPLITK2; s++) {
        float4 p = ((const float4*)P)[(size_t)s * MN4 + i];
        acc.x += p.x; acc.y += p.y; acc.z += p.z; acc.w += p.w;
    }
    ((float4*)out)[i] = acc;
}

extern "C" void kernel_launch(void* const* d_in, const int* in_sizes, int n_in,
                              void* d_out, int out_size, void* d_ws, size_t ws_size,
                              hipStream_t stream)
{
    const float* x  = (const float*)d_in[0];
    const float* WB = (const float*)d_in[1];
    const float* bB = (const float*)d_in[2];
    const float* WC = (const float*)d_in[3];
    const float* bC = (const float*)d_in[4];
    const float* A  = (const float*)d_in[5];

    char* ws = (char*)d_ws;
    size_t off = 0;
    bf16_t* xt   = (bf16_t*)(ws + off); off += (size_t)BATCH * SEQ * DIMSZ * 2;  // 4 MB
    bf16_t* WBt  = (bf16_t*)(ws + off); off += (size_t)HID * DIMSZ * 2;          // 2 MB
    bf16_t* Wt   = (bf16_t*)(ws + off); off += (size_t)DIMSZ * HID * 2;          // 2 MB
    bf16_t* bbuf = (bf16_t*)(ws + off); off += (size_t)BATCH * SEQ * HID * 2;    // 64 MB
    float* partials = (float*)(ws + off); off += (size_t)SPLITK2 * BATCH * SEQ * DIMSZ * 4;
    float* totals   = (float*)(ws + off); off += (size_t)BATCH * NCH * HID * 4;

    const int M = BATCH * SEQ;   // 8192

    prep_kernel<<<2048, 256, 0, stream>>>(x, WB, WC, xt, WBt, Wt);

    dim3 g1(M / 128, HID / 128);
    gemm1_fused<<<g1, 256, 0, stream>>>(xt, WBt, bB, A, bbuf, totals);

    dim3 g2(M / BM2, SPLITK2);
    gemm2_fused<<<g2, 256, 0, stream>>>(bbuf, Wt, A, totals, partials);
    reduce_out_kernel<<<(M * DIMSZ / 4 + 255) / 256, 256, 0, stream>>>(
        partials, bC, (float*)d_out, M * DIMSZ / 4);
}

// Round 11
// 152.822 us; speedup vs baseline: 1.3212x; 1.3212x over previous
//
#include <hip/hip_runtime.h>
#include <hip/hip_bf16.h>

#define DIMSZ 256
#define HID 4096
#define BATCH 4
#define SEQ 2048
#define NCH 64      // chunks per sequence (carry granularity)
#define CLEN 32     // chunk length
#define SPLITK2 4   // K-splits for fused GEMM2
#define KCHUNK (HID / SPLITK2)   // 1024 channels per block
#define BM2 64      // timesteps per fused-GEMM2 block

typedef __bf16 bf16_t;
typedef __bf16 bf16x8 __attribute__((ext_vector_type(8)));
typedef float  f32x4  __attribute__((ext_vector_type(4)));

__device__ __forceinline__ float sigmoidf_dev(float x) {
    return 1.0f / (1.0f + __expf(-x));
}

// async global->LDS, 16B/lane. LDS dest = wave-uniform base + lane*16.
__device__ __forceinline__ void load_lds16(const bf16_t* g, bf16_t* l) {
    __builtin_amdgcn_global_load_lds(
        (const __attribute__((address_space(1))) void*)g,
        (__attribute__((address_space(3))) void*)l,
        16, 0, 0);
}

__device__ __forceinline__ bf16x8 cvt8(const float* p) {
    bf16x8 o;
    #pragma unroll
    for (int j = 0; j < 8; j++) o[j] = (bf16_t)p[j];
    return o;
}

// ---------------- prep: fused fp32->bf16 convert + MFMA-frag swizzle ----------------
// xt : [ks][m16][lane][8]  ks=k>>5 (0..7),  m16=m>>4 (0..511)
// WBt: [ks][n16][lane][8]  ks 0..7, n16 0..255
// Wt : [ks][g][lane][8]    ks 0..127, g 0..15
__global__ void prep_kernel(const float* __restrict__ x,
                            const float* __restrict__ WB,
                            const float* __restrict__ WC,
                            bf16_t* __restrict__ xt,
                            bf16_t* __restrict__ WBt,
                            bf16_t* __restrict__ Wt) {
    int i = blockIdx.x * blockDim.x + threadIdx.x;   // 524288
    if (i < 262144) {                                // xt
        int lane = i & 63, m16 = (i >> 6) & 511, ks = i >> 15;
        int row = m16 * 16 + (lane & 15);
        int k   = ks * 32 + (lane >> 4) * 8;
        *(bf16x8*)&xt[(size_t)i * 8] = cvt8(&x[(size_t)row * DIMSZ + k]);
    } else if (i < 393216) {                         // WBt
        int j = i - 262144;
        int lane = j & 63, n16 = (j >> 6) & 255, ks = j >> 14;
        int row = n16 * 16 + (lane & 15);
        int k   = ks * 32 + (lane >> 4) * 8;
        *(bf16x8*)&WBt[(size_t)j * 8] = cvt8(&WB[(size_t)row * DIMSZ + k]);
    } else {                                         // Wt
        int j = i - 393216;
        int lane = j & 63, g = (j >> 6) & 15, ks = j >> 10;
        int row = g * 16 + (lane & 15);
        int k   = ks * 32 + (lane >> 4) * 8;
        *(bf16x8*)&Wt[(size_t)j * 8] = cvt8(&WC[(size_t)row * HID + k]);
    }
}

// ---------------- GEMM1 fused: b = x@WB^T + bB (bf16), + per-chunk totals ----------------
// Barrier-free K-loop: frags stream from pre-swizzled xt/WBt (L2-hot) to VGPRs.
__global__ __launch_bounds__(256)
void gemm1_fused(const bf16_t* __restrict__ xt, const bf16_t* __restrict__ WBt,
                 const float* __restrict__ bias, const float* __restrict__ Adecay,
                 bf16_t* __restrict__ Cg, float* __restrict__ totals)
{
    constexpr int N = HID;
    constexpr int LDTILE = 136;
    __shared__ bf16_t tile[128 * LDTILE];   // 34 KB

    const int tid = threadIdx.x, wave = tid >> 6, lane = tid & 63;
    const int wm = wave >> 1, wn = wave & 1, q = lane >> 4, r16 = lane & 15;
    const int mBase = blockIdx.x * 128, nBase = blockIdx.y * 128;
    const int m16Base = blockIdx.x * 8 + wm * 4;
    const int n16Base = blockIdx.y * 8 + wn * 4;

    f32x4 acc[4][4] = {};

    #pragma unroll 2
    for (int ks = 0; ks < 8; ks++) {
        bf16x8 af[4], bfr[4];
        #pragma unroll
        for (int mt = 0; mt < 4; mt++)
            af[mt] = *(const bf16x8*)&xt[(((size_t)ks * 512 + m16Base + mt) * 64 + lane) * 8];
        #pragma unroll
        for (int nt = 0; nt < 4; nt++)
            bfr[nt] = *(const bf16x8*)&WBt[(((size_t)ks * 256 + n16Base + nt) * 64 + lane) * 8];
        #pragma unroll
        for (int mt = 0; mt < 4; mt++)
            #pragma unroll
            for (int nt = 0; nt < 4; nt++)
                acc[mt][nt] = __builtin_amdgcn_mfma_f32_16x16x32_bf16(
                    af[mt], bfr[nt], acc[mt][nt], 0, 0, 0);
    }

    // acc (+bias) -> LDS tile
    #pragma unroll
    for (int nt = 0; nt < 4; nt++) {
        const int chl = wn * 64 + nt * 16 + r16;
        const float bv = bias[nBase + chl];
        #pragma unroll
        for (int mt = 0; mt < 4; mt++) {
            const int t0 = wm * 64 + mt * 16 + q * 4;
            #pragma unroll
            for (int rg = 0; rg < 4; rg++)
                tile[(t0 + rg) * LDTILE + chl] = (bf16_t)(acc[mt][nt][rg] + bv);
        }
    }
    __syncthreads();

    // coalesced writeback: 8 passes x (16 rows x 128 ch)
    #pragma unroll
    for (int p = 0; p < 8; p++) {
        const int t = p * 16 + (tid >> 4);
        const int ch8 = (tid & 15) << 3;
        *(bf16x8*)&Cg[(size_t)(mBase + t) * N + nBase + ch8] =
            *(const bf16x8*)&tile[t * LDTILE + ch8];
    }

    // chunk totals: 128 channels x 4 chunks
    #pragma unroll
    for (int t = 0; t < 2; t++) {
        int task = tid + t * 256;
        int ch = task & 127, ck = task >> 7;
        float a = sigmoidf_dev(Adecay[nBase + ch]);
        float tot = 0.f;
        #pragma unroll 8
        for (int i = 0; i < CLEN; i++)
            tot = a * tot + (float)tile[(ck * CLEN + i) * LDTILE + ch];
        int batch = mBase >> 11;
        int cg = ((mBase & 2047) >> 5) + ck;
        totals[(size_t)(batch * NCH + cg) * HID + nBase + ch] = tot;
    }
}

// ---------------- scan over chunk carries (restored from r9: parallel, cheap) ----------------
__global__ void scan_carries_kernel(const float* __restrict__ totals,
                                    const float* __restrict__ Adecay,
                                    float* __restrict__ carries)
{
    int gid = blockIdx.x * 64 + threadIdx.x;   // BATCH*HID
    int ch    = gid & (HID - 1);
    int batch = gid >> 12;
    float a = sigmoidf_dev(Adecay[ch]);
    float aC = a;
    #pragma unroll
    for (int i = 0; i < 5; i++) aC *= aC;      // a^32
    float carry = 0.f;
    #pragma unroll 8
    for (int c = 0; c < NCH; c++) {
        size_t idx = (size_t)(batch * NCH + c) * HID + ch;
        carries[idx] = carry;
        carry = aC * carry + totals[idx];
    }
}

// ---------------- fused scan + GEMM2 split-K, barrier-free MFMA K-loop ----------------
// Scan split into 2x32-step chains: chain0 seeded carries[chunk0], chain1 seeded
// a^32*carry0 + totals[chunk0] (two independent coalesced loads, no serial chain).
__global__ __launch_bounds__(256)
void gemm2_fused(const bf16_t* __restrict__ bv, const bf16_t* __restrict__ Wt,
                 const float* __restrict__ Adecay, const float* __restrict__ carries,
                 const float* __restrict__ totals, float* __restrict__ P)
{
    constexpr int N = DIMSZ;
    constexpr int CKSTRIDE = BM2 * 32 + 32;    // +64B stagger between ck slabs
    __shared__ bf16_t hs[8 * CKSTRIDE];        // 32.5 KB

    const int tid = threadIdx.x, wave = tid >> 6, lane = tid & 63;
    const int q = lane >> 4, r16 = lane & 15;
    const int mBase = blockIdx.x * BM2;
    const int kBase = blockIdx.y * KCHUNK;
    const int batch = mBase >> 11;
    const int chunk0 = (mBase & 2047) >> 5;

    f32x4 acc[4][4] = {};

    for (int s = 0; s < KCHUNK / 256; s++) {
        const int chSlab = kBase + s * 256;

        // all waves must finish the previous slab's hs reads before DMA writes land
        if (s > 0) __syncthreads();

        // stage b-slab -> hs: wave w covers cks {2w, 2w+1}, 4 row-groups each
        #pragma unroll
        for (int i = 0; i < 8; i++) {
            int ck = wave * 2 + (i >> 2);
            int g  = i & 3;
            load_lds16(&bv[(size_t)(mBase + g * 16 + (lane >> 2)) * HID
                           + chSlab + ck * 32 + ((lane & 3) << 3)],
                       &hs[ck * CKSTRIDE + g * 512]);
        }

        // seeds (independent loads, issued during staging)
        const int ck = tid >> 5, ch = tid & 31;
        const int c = chSlab + ck * 32 + ch;
        const float a = sigmoidf_dev(Adecay[c]);
        float aC = a;
        #pragma unroll
        for (int i = 0; i < 5; i++) aC *= aC;  // a^32
        const size_t seedIdx = (size_t)(batch * NCH + chunk0) * HID + c;
        const float carry0 = carries[seedIdx];
        const float carry1 = aC * carry0 + totals[seedIdx];

        __syncthreads();   // staging drained

        // in-place scan: 2 independent 32-step chains (chunk-aligned seeds)
        {
            bf16_t* hp = &hs[ck * CKSTRIDE + ch];
            float st0 = carry0, st1 = carry1;
            #pragma unroll 8
            for (int t = 0; t < 32; t++) {
                st0 = a * st0 + (float)hp[t * 32];
                st1 = a * st1 + (float)hp[(t + 32) * 32];
                hp[t * 32]        = (bf16_t)st0;
                hp[(t + 32) * 32] = (bf16_t)st1;
            }
        }
        __syncthreads();   // hs = h, visible to all waves

        // barrier-free MFMA k-steps; B-frags direct from swizzled global
        const int ksBase = (kBase >> 5) + s * 8;
        #pragma unroll 2
        for (int cki = 0; cki < 8; cki++) {
            bf16x8 af[4], bfr[4];
            #pragma unroll
            for (int nt = 0; nt < 4; nt++)
                bfr[nt] = *(const bf16x8*)&Wt[
                    (((size_t)(ksBase + cki) * 16 + wave * 4 + nt) * 64 + lane) * 8];
            #pragma unroll
            for (int mt = 0; mt < 4; mt++)
                af[mt] = *(const bf16x8*)&hs[cki * CKSTRIDE + (mt * 16 + r16) * 32 + q * 8];
            #pragma unroll
            for (int mt = 0; mt < 4; mt++)
                #pragma unroll
                for (int nt = 0; nt < 4; nt++)
                    acc[mt][nt] = __builtin_amdgcn_mfma_f32_16x16x32_bf16(
                        af[mt], bfr[nt], acc[mt][nt], 0, 0, 0);
        }
    }

    // epilogue: fp32 partials
    float* Pb = P + (size_t)blockIdx.y * (BATCH * SEQ) * N;
    #pragma unroll
    for (int nt = 0; nt < 4; nt++) {
        const int col = wave * 64 + nt * 16 + r16;
        #pragma unroll
        for (int mt = 0; mt < 4; mt++) {
            const int row0 = mBase + mt * 16 + q * 4;
            #pragma unroll
            for (int rg = 0; rg < 4; rg++)
                Pb[(size_t)(row0 + rg) * N + col] = acc[mt][nt][rg];
        }
    }
}

// ---------------- reduce partials + bias -> d_out ----------------
__global__ void reduce_out_kernel(const float* __restrict__ P,
                                  const float* __restrict__ bias,
                                  float* __restrict__ out, int MN4) {
    int i = blockIdx.x * blockDim.x + threadIdx.x;
    if (i >= MN4) return;
    int n4 = i & (DIMSZ / 4 - 1);
    float4 acc = ((const float4*)bias)[n4];
    #pragma unroll
    for (int s = 0; s < SPLITK2; s++) {
        float4 p = ((const float4*)P)[(size_t)s * MN4 + i];
        acc.x += p.x; acc.y += p.y; acc.z += p.z; acc.w += p.w;
    }
    ((float4*)out)[i] = acc;
}

extern "C" void kernel_launch(void* const* d_in, const int* in_sizes, int n_in,
                              void* d_out, int out_size, void* d_ws, size_t ws_size,
                              hipStream_t stream)
{
    const float* x  = (const float*)d_in[0];
    const float* WB = (const float*)d_in[1];
    const float* bB = (const float*)d_in[2];
    const float* WC = (const float*)d_in[3];
    const float* bC = (const float*)d_in[4];
    const float* A  = (const float*)d_in[5];

    char* ws = (char*)d_ws;
    size_t off = 0;
    bf16_t* xt   = (bf16_t*)(ws + off); off += (size_t)BATCH * SEQ * DIMSZ * 2;  // 4 MB
    bf16_t* WBt  = (bf16_t*)(ws + off); off += (size_t)HID * DIMSZ * 2;          // 2 MB
    bf16_t* Wt   = (bf16_t*)(ws + off); off += (size_t)DIMSZ * HID * 2;          // 2 MB
    bf16_t* bbuf = (bf16_t*)(ws + off); off += (size_t)BATCH * SEQ * HID * 2;    // 64 MB
    float* partials = (float*)(ws + off); off += (size_t)SPLITK2 * BATCH * SEQ * DIMSZ * 4;
    float* totals   = (float*)(ws + off); off += (size_t)BATCH * NCH * HID * 4;
    float* carries  = (float*)(ws + off); off += (size_t)BATCH * NCH * HID * 4;

    const int M = BATCH * SEQ;   // 8192

    prep_kernel<<<2048, 256, 0, stream>>>(x, WB, WC, xt, WBt, Wt);

    dim3 g1(M / 128, HID / 128);
    gemm1_fused<<<g1, 256, 0, stream>>>(xt, WBt, bB, A, bbuf, totals);

    scan_carries_kernel<<<256, 64, 0, stream>>>(totals, A, carries);

    dim3 g2(M / BM2, SPLITK2);
    gemm2_fused<<<g2, 256, 0, stream>>>(bbuf, Wt, A, carries, totals, partials);
    reduce_out_kernel<<<(M * DIMSZ / 4 + 255) / 256, 256, 0, stream>>>(
        partials, bC, (float*)d_out, M * DIMSZ / 4);
}